// Round 18
// baseline (111.040 us; speedup 1.0000x reference)
//
#include <hip/hip_runtime.h>
#include <math.h>

#define DIMX 256
#define NFEAT 32
#define BATCH 512
#define HEADS 8
#define DHEAD 32
#define KNN 17
#define QKV_W 768
// DHEAD^-0.5 * log2(e): scores pre-scaled so softmax uses native exp2
#define SCALE_L2 0.25503486f

typedef unsigned int uint;
typedef unsigned short ushort_t;
typedef __attribute__((ext_vector_type(8))) short short8_t;   // 8 bf16 (4 VGPRs)
typedef __attribute__((ext_vector_type(4))) float float4_t;   // MFMA acc

__device__ inline float bf_lo(uint u) { return __uint_as_float(u << 16); }
__device__ inline float bf_hi(uint u) { return __uint_as_float(u & 0xffff0000u); }
__device__ inline ushort_t f2bf(float f) {
  uint u = __float_as_uint(f);
  return (ushort_t)((u + 0x7fffu + ((u >> 16) & 1u)) >> 16);
}

#if defined(__has_builtin)
#if __has_builtin(__builtin_amdgcn_fdot2_f32_bf16)
#define HAVE_DOT2 1
#endif
#if __has_builtin(__builtin_amdgcn_exp2f)
#define EXP2(x) __builtin_amdgcn_exp2f(x)
#endif
#endif
#ifndef EXP2
#define EXP2(x) exp2f(x)
#endif

#ifdef HAVE_DOT2
typedef __attribute__((ext_vector_type(2))) __bf16 bf16x2_t;
__device__ inline float dot2bf(uint a, uint b, float c) {
  return __builtin_amdgcn_fdot2_f32_bf16(
      __builtin_bit_cast(bf16x2_t, a), __builtin_bit_cast(bf16x2_t, b), c, false);
}
#else
__device__ inline float dot2bf(uint a, uint b, float c) {
  return c + bf_lo(a)*bf_lo(b) + bf_hi(a)*bf_hi(b);
}
#endif

__device__ inline void gload16(const ushort_t* g, ushort_t* l) {
  // async global->LDS, 16B/lane; LDS dest = wave-uniform base + lane*16
  __builtin_amdgcn_global_load_lds(
      (const __attribute__((address_space(1))) void*)g,
      (__attribute__((address_space(3))) void*)l, 16, 0, 0);
}

// ---------------- K1: repr (+x->bf16 cast) for bid<512; W transposes for bid>=512 --------------
__global__ __launch_bounds__(256, 2) void repr_prep_kernel(
    const float* __restrict__ x, const float* __restrict__ W_repr,
    const float* __restrict__ b_repr, const float* __restrict__ Wq,
    const float* __restrict__ Wo, float* __restrict__ normed,
    ushort_t* __restrict__ xbf, ushort_t* __restrict__ wqT, ushort_t* __restrict__ woT) {
  __shared__ float smem[64*65];       // 16.6 KB, shared by both roles
  int bid = blockIdx.x, t = threadIdx.x;
  if (bid < BATCH) {
    float* mean_s = smem;
    float* red = smem + 256;
    int b = bid;
    float s = 0.f;
#pragma unroll
    for (int n = 0; n < NFEAT; ++n) {
      float v = x[(size_t)(b*NFEAT+n)*DIMX + t];
      s += v;
      xbf[(size_t)(b*NFEAT+n)*DIMX + t] = f2bf(v);
    }
    mean_s[t] = s * (1.0f/NFEAT);
    __syncthreads();
    float a0 = b_repr[t], a1 = 0.f, a2 = 0.f, a3 = 0.f;
#pragma unroll 8
    for (int d = 0; d < 64; ++d) {
      a0 += mean_s[d      ] * W_repr[(d      )*DIMX + t];
      a1 += mean_s[d +  64] * W_repr[(d +  64)*DIMX + t];
      a2 += mean_s[d + 128] * W_repr[(d + 128)*DIMX + t];
      a3 += mean_s[d + 192] * W_repr[(d + 192)*DIMX + t];
    }
    float acc = (a0 + a1) + (a2 + a3);
    red[t] = acc*acc;
    __syncthreads();
    for (int off = 128; off > 0; off >>= 1) {
      if (t < off) red[t] += red[t+off];
      __syncthreads();
    }
    normed[b*DIMX + t] = acc / sqrtf(red[0]);
  } else {
    // 64x64 tiled transpose-cast: W_qkv [256][768]->wqT [768][256]; W_out->woT
    int pb = bid - BATCH;
    const float* W; ushort_t* WT; int NN, tx, ty;
    if (pb < 48) { W = Wq; WT = wqT; NN = QKV_W; tx = pb % 12; ty = pb / 12; }
    else { int b2 = pb - 48; W = Wo; WT = woT; NN = DIMX; tx = b2 % 4; ty = b2 / 4; }
    float (*tile)[65] = (float(*)[65])smem;
#pragma unroll
    for (int i = 0; i < 4; ++i) {
      int c = t + 256*i;
      int r = c >> 4, c4 = (c & 15) * 4;
      *(float4*)&tile[r][c4] = *(const float4*)&W[(size_t)(ty*64 + r)*NN + tx*64 + c4];
    }
    __syncthreads();
    int rr = t >> 2, cc0 = (t & 3) * 16;
    uint ow[8];
#pragma unroll
    for (int k = 0; k < 8; ++k)
      ow[k] = (uint)f2bf(tile[cc0 + 2*k][rr]) | ((uint)f2bf(tile[cc0 + 2*k + 1][rr]) << 16);
    uint4 o0 = {ow[0], ow[1], ow[2], ow[3]};
    uint4 o1 = {ow[4], ow[5], ow[6], ow[7]};
    size_t obase = (size_t)(tx*64 + rr)*DIMX + ty*64 + cc0;
    *(uint4*)&WT[obase]     = o0;
    *(uint4*)&WT[obase + 8] = o1;
  }
}

// ---------------- MFMA GEMM body: 128x128 tile, BK=64, double-buffered global_load_lds --------
__device__ __forceinline__ void gemm_body(
    ushort_t (&As)[2][128][64], ushort_t (&Bs)[2][128][64],
    const ushort_t* __restrict__ A, const ushort_t* __restrict__ Bt,
    ushort_t* __restrict__ Cout, int N, int K, int row0, int col0) {
  int t = threadIdx.x, l = t & 63, w = t >> 6;
  int wr = w >> 1, wc = w & 1;
  int srcRow = l >> 3, srcCol = (l & 7) * 8;
  float4_t acc[4][4] = {};
  int nkt = K >> 6;
#pragma unroll
  for (int i = 0; i < 4; ++i) {
    int ar = w*32 + i*8;
    gload16(&A [(size_t)(row0+ar+srcRow)*K + srcCol], &As[0][ar][0]);
    gload16(&Bt[(size_t)(col0+ar+srcRow)*K + srcCol], &Bs[0][ar][0]);
  }
  __syncthreads();
  int cur = 0;
  for (int kt = 0; kt < nkt; ++kt) {
    if (kt + 1 < nkt) {
      int k1 = (kt + 1) << 6;
#pragma unroll
      for (int i = 0; i < 4; ++i) {
        int ar = w*32 + i*8;
        gload16(&A [(size_t)(row0+ar+srcRow)*K + k1 + srcCol], &As[cur^1][ar][0]);
        gload16(&Bt[(size_t)(col0+ar+srcRow)*K + k1 + srcCol], &Bs[cur^1][ar][0]);
      }
    }
#pragma unroll
    for (int ks = 0; ks < 2; ++ks) {
      int kk = ks*32 + (l >> 4)*8;
      short8_t a[4], b[4];
#pragma unroll
      for (int m = 0; m < 4; ++m) a[m] = *(short8_t*)&As[cur][wr*64 + m*16 + (l & 15)][kk];
#pragma unroll
      for (int n = 0; n < 4; ++n) b[n] = *(short8_t*)&Bs[cur][wc*64 + n*16 + (l & 15)][kk];
#pragma unroll
      for (int m = 0; m < 4; ++m)
#pragma unroll
        for (int n = 0; n < 4; ++n)
          acc[m][n] = __builtin_amdgcn_mfma_f32_16x16x32_bf16(a[m], b[n], acc[m][n], 0, 0, 0);
    }
    __syncthreads();   // drains vmcnt (next tile staged) + protects buf reuse
    cur ^= 1;
  }
  int crow = (l >> 4) * 4, ccol = l & 15;
#pragma unroll
  for (int m = 0; m < 4; ++m)
#pragma unroll
    for (int n = 0; n < 4; ++n) {
      int col = col0 + wc*64 + n*16 + ccol;
#pragma unroll
      for (int r = 0; r < 4; ++r) {
        int row = row0 + wr*64 + m*16 + crow + r;
        Cout[(size_t)row*N + col] = f2bf(acc[m][n][r]);
      }
    }
}

// ---------------- K2: qkv GEMM (bid<768) + sim GEMM (bid>=768), one launch --------------------
__global__ __launch_bounds__(256, 2) void simqkv_kernel(
    const ushort_t* __restrict__ xbf, const ushort_t* __restrict__ wqT,
    ushort_t* __restrict__ qkv, const float* __restrict__ normed,
    float* __restrict__ sims) {
  __shared__ ushort_t As[2][128][64];
  __shared__ ushort_t Bs[2][128][64];
  int bid = blockIdx.x, t = threadIdx.x;
  if (bid < 768) {
    gemm_body(As, Bs, xbf, wqT, qkv, QKV_W, DIMX, (bid & 127) * 128, (bid >> 7) * 128);
  } else {
    int sid = bid - 768;
    int i0 = (sid & 15) * 32, j0 = (sid >> 4) * 32;
    float (*sA)[68] = (float(*)[68])(&As[0][0][0]);   // 8.7 KB, fits in As
    float (*sB)[68] = (float(*)[68])(&Bs[0][0][0]);
    int tx = t & 15, ty = t >> 4;
    float acc00 = 0.f, acc01 = 0.f, acc10 = 0.f, acc11 = 0.f;
    for (int k0 = 0; k0 < DIMX; k0 += 64) {
#pragma unroll
      for (int c = t; c < 512; c += 256) {
        int r = c >> 4, cc = (c & 15) * 4;
        *(float4*)&sA[r][cc] = *(const float4*)&normed[(size_t)(i0 + r)*DIMX + k0 + cc];
        *(float4*)&sB[r][cc] = *(const float4*)&normed[(size_t)(j0 + r)*DIMX + k0 + cc];
      }
      __syncthreads();
#pragma unroll 16
      for (int kk = 0; kk < 64; ++kk) {
        float a0 = sA[ty*2][kk],   a1 = sA[ty*2+1][kk];
        float b0 = sB[tx*2][kk],   b1 = sB[tx*2+1][kk];
        acc00 += a0*b0; acc01 += a0*b1; acc10 += a1*b0; acc11 += a1*b1;
      }
      __syncthreads();
    }
    sims[(size_t)(i0+ty*2  )*BATCH + j0+tx*2  ] = acc00;
    sims[(size_t)(i0+ty*2  )*BATCH + j0+tx*2+1] = acc01;
    sims[(size_t)(i0+ty*2+1)*BATCH + j0+tx*2  ] = acc10;
    sims[(size_t)(i0+ty*2+1)*BATCH + j0+tx*2+1] = acc11;
  }
}

// ---------------- K3: top-17 via rank selection (exact lax.top_k order) ------------------------
__global__ __launch_bounds__(256, 8) void topk_rank(const float* __restrict__ sims,
                                                    int* __restrict__ knn) {
  int i = blockIdx.x, t = threadIdx.x;
  __shared__ float row[BATCH];
  row[t]       = sims[(size_t)i*BATCH + t];
  row[t + 256] = sims[(size_t)i*BATCH + t + 256];
  __syncthreads();
  float v1 = row[t], v2 = row[t + 256];
  int i1 = t, i2 = t + 256;
  int r1 = 0, r2 = 0;
  const float4* r4 = (const float4*)row;
#pragma unroll 8
  for (int c = 0; c < BATCH/4; ++c) {
    float4 q = r4[c];            // LDS broadcast (same addr all lanes)
    int base = c * 4;
    r1 += (q.x > v1 || (q.x == v1 && base+0 < i1));
    r1 += (q.y > v1 || (q.y == v1 && base+1 < i1));
    r1 += (q.z > v1 || (q.z == v1 && base+2 < i1));
    r1 += (q.w > v1 || (q.w == v1 && base+3 < i1));
    r2 += (q.x > v2 || (q.x == v2 && base+0 < i2));
    r2 += (q.y > v2 || (q.y == v2 && base+1 < i2));
    r2 += (q.z > v2 || (q.z == v2 && base+2 < i2));
    r2 += (q.w > v2 || (q.w == v2 && base+3 < i2));
  }
  if (r1 < KNN) knn[i*32 + r1] = i1;
  if (r2 < KNN) knn[i*32 + r2] = i2;
}

// ---------------- K4: attention (champion phase-pairs) + fused MFMA out-projection ------------
// Attention rows stay in LDS (bf16 [16][264], rows 8-15 zeroed); block epilogue runs the
// out-projection as 32 MFMAs/wave (M=16 padded, 4 N-frags x 8 K-steps), B-frags straight
// from L2-resident woT. Deletes out_gemm launch + attn_out round-trip; same roundings.
#define NF_BLK 8
#define OLD_STRIDE 264   // 528B rows -> bank offset 4/row -> 2-way (free) A-frag reads
__global__ __launch_bounds__(256, 8) void attn_kernel(
    const ushort_t* __restrict__ qkv, const int* __restrict__ knn,
    const ushort_t* __restrict__ woT, const float* __restrict__ b_out,
    float* __restrict__ out) {
  int b = blockIdx.x, g = blockIdx.y, t = threadIdx.x;
  int n0 = g * NF_BLK;
  __shared__ float sc_s[2][KNN][HEADS];
  __shared__ int idxp[KNN];            // precomputed qkv row offset: idx*NFEAT*QKV_W
  __shared__ ushort_t o_lds[16][OLD_STRIDE];   // 8.4 KB
  if (t < KNN) idxp[t] = knn[b*32 + t] * (NFEAT*QKV_W);
  for (int i = t; i < 8*OLD_STRIDE; i += 256)  // zero pad rows 8..15
    o_lds[8 + i/OLD_STRIDE][i % OLD_STRIDE] = 0;
  __syncthreads();

  for (int np = 0; np < NF_BLK; np += 2) {
    int n = n0 + np;
    // ---- phase A: scores for features n, n+1 (272 jobs over 256 lanes) ----
    for (int job = t; job < 2*KNN*HEADS; job += 256) {
      int f = (job >= KNN*HEADS) ? 1 : 0;
      int r = job - f*KNN*HEADS;
      int j = r >> 3, h = r & 7;
      const uint4* qp = (const uint4*)&qkv[(size_t)(b*NFEAT + n + f)*QKV_W + h*DHEAD];
      const uint4* kp = (const uint4*)&qkv[(size_t)(idxp[j] + (n + f)*QKV_W + 256 + h*DHEAD)];
      float s0 = 0.f, s1 = 0.f;
#pragma unroll
      for (int i = 0; i < 4; ++i) {
        uint4 qv = qp[i], kv = kp[i];
        s0 = dot2bf(kv.x, qv.x, s0); s1 = dot2bf(kv.y, qv.y, s1);
        s0 = dot2bf(kv.z, qv.z, s0); s1 = dot2bf(kv.w, qv.w, s1);
      }
      sc_s[f][j][h] = (s0 + s1) * SCALE_L2;
    }
    __syncthreads();
    // ---- phase B: register softmax (exp2, in-place) + PV -> LDS rows ----
    {
      int f = t >> 7, p = t & 127, h = p >> 4;
      float sv[KNN];
#pragma unroll
      for (int j = 0; j < KNN; ++j) sv[j] = sc_s[f][j][h];
      float m = sv[0];
#pragma unroll
      for (int j = 1; j < KNN; ++j) m = fmaxf(m, sv[j]);
      float sum = 0.f;
#pragma unroll
      for (int j = 0; j < KNN; ++j) { sv[j] = EXP2(sv[j] - m); sum += sv[j]; }
      float inv = 1.0f / sum;
      int voff = (n + f)*QKV_W + 512 + p*2;
      float alo = 0.f, ahi = 0.f;
#pragma unroll
      for (int j = 0; j < KNN; ++j) {
        uint wv = *(const uint*)&qkv[(size_t)(idxp[j] + voff)];
        alo += sv[j] * bf_lo(wv);
        ahi += sv[j] * bf_hi(wv);
      }
      *(uint*)&o_lds[np + f][p*2] =
          (uint)f2bf(alo * inv) | ((uint)f2bf(ahi * inv) << 16);
    }
    __syncthreads();
  }

  // ---- fused out-projection: [16][256] (8 real rows) @ woT^T, 32 MFMAs/wave ----
  int l = t & 63, w = t >> 6;
  int arow = l & 15, koff = (l >> 4) * 8;
  float4_t acc[4] = {};
#pragma unroll
  for (int ks = 0; ks < 8; ++ks) {
    short8_t a = *(short8_t*)&o_lds[arow][ks*32 + koff];
#pragma unroll
    for (int nf = 0; nf < 4; ++nf) {
      short8_t bf = *(const short8_t*)&woT[(size_t)(w*64 + nf*16 + arow)*DIMX + ks*32 + koff];
      acc[nf] = __builtin_amdgcn_mfma_f32_16x16x32_bf16(a, bf, acc[nf], 0, 0, 0);
    }
  }
  int crow4 = (l >> 4) * 4, ccol = l & 15;
  if (crow4 < 8) {
#pragma unroll
    for (int nf = 0; nf < 4; ++nf) {
      int col = w*64 + nf*16 + ccol;
      float bias = b_out[col];
#pragma unroll
      for (int r = 0; r < 4; ++r) {
        int row = crow4 + r;
        out[(size_t)(b*NFEAT + n0 + row)*DIMX + col] = acc[nf][r] + bias;
      }
    }
  }
}

extern "C" void kernel_launch(void* const* d_in, const int* in_sizes, int n_in,
                              void* d_out, int out_size, void* d_ws, size_t ws_size,
                              hipStream_t stream) {
  const float* x      = (const float*)d_in[0];
  const float* W_qkv  = (const float*)d_in[1];
  const float* W_out  = (const float*)d_in[2];
  const float* b_out  = (const float*)d_in[3];
  const float* W_repr = (const float*)d_in[4];
  const float* b_repr = (const float*)d_in[5];
  float* out = (float*)d_out;

  ushort_t* qkv      = (ushort_t*)d_ws;                        // 16384*768 bf16
  ushort_t* xbf      = qkv + (size_t)16384*QKV_W;              // 16384*256
  ushort_t* wqT      = xbf + (size_t)16384*DIMX;               // 768*256
  ushort_t* woT      = wqT + (size_t)QKV_W*DIMX;               // 256*256
  float*    normed   = (float*)(woT + (size_t)DIMX*DIMX);
  float*    sims     = normed + (size_t)BATCH*DIMX;            // 512*512 f32
  int*      knn      = (int*)(sims + (size_t)BATCH*BATCH);

  repr_prep_kernel<<<BATCH + 64, 256, 0, stream>>>(
      x, W_repr, b_repr, W_qkv, W_out, normed, xbf, wqT, woT);
  simqkv_kernel<<<768 + 256, 256, 0, stream>>>(xbf, wqT, qkv, normed, sims);
  topk_rank<<<BATCH, 256, 0, stream>>>(sims, knn);
  attn_kernel<<<dim3(BATCH, NFEAT/NF_BLK), 256, 0, stream>>>(qkv, knn, woT, b_out, out);
}

// Round 19
// 94.261 us; speedup vs baseline: 1.1780x; 1.1780x over previous
//
#include <hip/hip_runtime.h>
#include <math.h>

#define DIMX 256
#define NFEAT 32
#define BATCH 512
#define HEADS 8
#define DHEAD 32
#define KNN 17
#define QKV_W 768
// DHEAD^-0.5 * log2(e): scores pre-scaled so softmax uses native exp2
#define SCALE_L2 0.25503486f

typedef unsigned int uint;
typedef unsigned short ushort_t;
typedef __attribute__((ext_vector_type(8))) short short8_t;   // 8 bf16 (4 VGPRs)
typedef __attribute__((ext_vector_type(4))) float float4_t;   // MFMA acc

__device__ inline float bf_lo(uint u) { return __uint_as_float(u << 16); }
__device__ inline float bf_hi(uint u) { return __uint_as_float(u & 0xffff0000u); }
__device__ inline ushort_t f2bf(float f) {
  uint u = __float_as_uint(f);
  return (ushort_t)((u + 0x7fffu + ((u >> 16) & 1u)) >> 16);
}

#if defined(__has_builtin)
#if __has_builtin(__builtin_amdgcn_fdot2_f32_bf16)
#define HAVE_DOT2 1
#endif
#if __has_builtin(__builtin_amdgcn_exp2f)
#define EXP2(x) __builtin_amdgcn_exp2f(x)
#endif
#endif
#ifndef EXP2
#define EXP2(x) exp2f(x)
#endif

#ifdef HAVE_DOT2
typedef __attribute__((ext_vector_type(2))) __bf16 bf16x2_t;
__device__ inline float dot2bf(uint a, uint b, float c) {
  return __builtin_amdgcn_fdot2_f32_bf16(
      __builtin_bit_cast(bf16x2_t, a), __builtin_bit_cast(bf16x2_t, b), c, false);
}
#else
__device__ inline float dot2bf(uint a, uint b, float c) {
  return c + bf_lo(a)*bf_lo(b) + bf_hi(a)*bf_hi(b);
}
#endif

__device__ inline void gload16(const ushort_t* g, ushort_t* l) {
  // async global->LDS, 16B/lane; LDS dest = wave-uniform base + lane*16
  __builtin_amdgcn_global_load_lds(
      (const __attribute__((address_space(1))) void*)g,
      (__attribute__((address_space(3))) void*)l, 16, 0, 0);
}

// ---------------- K1: repr (+x->bf16 cast) for bid<512; W transposes for bid>=512 --------------
__global__ __launch_bounds__(256, 2) void repr_prep_kernel(
    const float* __restrict__ x, const float* __restrict__ W_repr,
    const float* __restrict__ b_repr, const float* __restrict__ Wq,
    const float* __restrict__ Wo, float* __restrict__ normed,
    ushort_t* __restrict__ xbf, ushort_t* __restrict__ wqT, ushort_t* __restrict__ woT) {
  __shared__ float smem[64*65];       // 16.6 KB, shared by both roles
  int bid = blockIdx.x, t = threadIdx.x;
  if (bid < BATCH) {
    float* mean_s = smem;
    float* red = smem + 256;
    int b = bid;
    float s = 0.f;
#pragma unroll
    for (int n = 0; n < NFEAT; ++n) {
      float v = x[(size_t)(b*NFEAT+n)*DIMX + t];
      s += v;
      xbf[(size_t)(b*NFEAT+n)*DIMX + t] = f2bf(v);
    }
    mean_s[t] = s * (1.0f/NFEAT);
    __syncthreads();
    float a0 = b_repr[t], a1 = 0.f, a2 = 0.f, a3 = 0.f;
#pragma unroll 8
    for (int d = 0; d < 64; ++d) {
      a0 += mean_s[d      ] * W_repr[(d      )*DIMX + t];
      a1 += mean_s[d +  64] * W_repr[(d +  64)*DIMX + t];
      a2 += mean_s[d + 128] * W_repr[(d + 128)*DIMX + t];
      a3 += mean_s[d + 192] * W_repr[(d + 192)*DIMX + t];
    }
    float acc = (a0 + a1) + (a2 + a3);
    red[t] = acc*acc;
    __syncthreads();
    for (int off = 128; off > 0; off >>= 1) {
      if (t < off) red[t] += red[t+off];
      __syncthreads();
    }
    normed[b*DIMX + t] = acc / sqrtf(red[0]);
  } else {
    // 64x64 tiled transpose-cast: W_qkv [256][768]->wqT [768][256]; W_out->woT
    int pb = bid - BATCH;
    const float* W; ushort_t* WT; int NN, tx, ty;
    if (pb < 48) { W = Wq; WT = wqT; NN = QKV_W; tx = pb % 12; ty = pb / 12; }
    else { int b2 = pb - 48; W = Wo; WT = woT; NN = DIMX; tx = b2 % 4; ty = b2 / 4; }
    float (*tile)[65] = (float(*)[65])smem;
#pragma unroll
    for (int i = 0; i < 4; ++i) {
      int c = t + 256*i;
      int r = c >> 4, c4 = (c & 15) * 4;
      *(float4*)&tile[r][c4] = *(const float4*)&W[(size_t)(ty*64 + r)*NN + tx*64 + c4];
    }
    __syncthreads();
    int rr = t >> 2, cc0 = (t & 3) * 16;
    uint ow[8];
#pragma unroll
    for (int k = 0; k < 8; ++k)
      ow[k] = (uint)f2bf(tile[cc0 + 2*k][rr]) | ((uint)f2bf(tile[cc0 + 2*k + 1][rr]) << 16);
    uint4 o0 = {ow[0], ow[1], ow[2], ow[3]};
    uint4 o1 = {ow[4], ow[5], ow[6], ow[7]};
    size_t obase = (size_t)(tx*64 + rr)*DIMX + ty*64 + cc0;
    *(uint4*)&WT[obase]     = o0;
    *(uint4*)&WT[obase + 8] = o1;
  }
}

// ---------------- MFMA GEMM body: 128x128 tile, BK=64, double-buffered global_load_lds --------
template<bool OUTF32>
__device__ __forceinline__ void gemm_body(
    ushort_t (&As)[2][128][64], ushort_t (&Bs)[2][128][64],
    const ushort_t* __restrict__ A, const ushort_t* __restrict__ Bt,
    void* __restrict__ Cout, const float* __restrict__ bias,
    int M, int N, int K, int row0, int col0) {
  int t = threadIdx.x, l = t & 63, w = t >> 6;
  int wr = w >> 1, wc = w & 1;
  int srcRow = l >> 3, srcCol = (l & 7) * 8;
  float4_t acc[4][4] = {};
  int nkt = K >> 6;
#pragma unroll
  for (int i = 0; i < 4; ++i) {
    int ar = w*32 + i*8;
    gload16(&A [(size_t)(row0+ar+srcRow)*K + srcCol], &As[0][ar][0]);
    gload16(&Bt[(size_t)(col0+ar+srcRow)*K + srcCol], &Bs[0][ar][0]);
  }
  __syncthreads();
  int cur = 0;
  for (int kt = 0; kt < nkt; ++kt) {
    if (kt + 1 < nkt) {
      int k1 = (kt + 1) << 6;
#pragma unroll
      for (int i = 0; i < 4; ++i) {
        int ar = w*32 + i*8;
        gload16(&A [(size_t)(row0+ar+srcRow)*K + k1 + srcCol], &As[cur^1][ar][0]);
        gload16(&Bt[(size_t)(col0+ar+srcRow)*K + k1 + srcCol], &Bs[cur^1][ar][0]);
      }
    }
#pragma unroll
    for (int ks = 0; ks < 2; ++ks) {
      int kk = ks*32 + (l >> 4)*8;
      short8_t a[4], b[4];
#pragma unroll
      for (int m = 0; m < 4; ++m) a[m] = *(short8_t*)&As[cur][wr*64 + m*16 + (l & 15)][kk];
#pragma unroll
      for (int n = 0; n < 4; ++n) b[n] = *(short8_t*)&Bs[cur][wc*64 + n*16 + (l & 15)][kk];
#pragma unroll
      for (int m = 0; m < 4; ++m)
#pragma unroll
        for (int n = 0; n < 4; ++n)
          acc[m][n] = __builtin_amdgcn_mfma_f32_16x16x32_bf16(a[m], b[n], acc[m][n], 0, 0, 0);
    }
    __syncthreads();   // drains vmcnt (next tile staged) + protects buf reuse
    cur ^= 1;
  }
  int crow = (l >> 4) * 4, ccol = l & 15;
#pragma unroll
  for (int m = 0; m < 4; ++m)
#pragma unroll
    for (int n = 0; n < 4; ++n) {
      int col = col0 + wc*64 + n*16 + ccol;
#pragma unroll
      for (int r = 0; r < 4; ++r) {
        int row = row0 + wr*64 + m*16 + crow + r;
        if (OUTF32) ((float*)Cout)[(size_t)row*N + col] = acc[m][n][r] + bias[col];
        else        ((ushort_t*)Cout)[(size_t)row*N + col] = f2bf(acc[m][n][r]);
      }
    }
}

template<bool OUTF32>
__global__ __launch_bounds__(256, 2) void mfma_gemm(
    const ushort_t* __restrict__ A, const ushort_t* __restrict__ Bt,
    void* __restrict__ Cout, const float* __restrict__ bias, int M, int N, int K) {
  __shared__ ushort_t As[2][128][64];
  __shared__ ushort_t Bs[2][128][64];
  gemm_body<OUTF32>(As, Bs, A, Bt, Cout, bias, M, N, K, blockIdx.x*128, blockIdx.y*128);
}

// ---------------- K2: qkv GEMM (bid<768) + sim GEMM (bid>=768), one launch --------------------
__global__ __launch_bounds__(256, 2) void simqkv_kernel(
    const ushort_t* __restrict__ xbf, const ushort_t* __restrict__ wqT,
    ushort_t* __restrict__ qkv, const float* __restrict__ normed,
    float* __restrict__ sims) {
  __shared__ ushort_t As[2][128][64];
  __shared__ ushort_t Bs[2][128][64];
  int bid = blockIdx.x, t = threadIdx.x;
  if (bid < 768) {
    gemm_body<false>(As, Bs, xbf, wqT, qkv, nullptr, 16384, QKV_W, DIMX,
                     (bid & 127) * 128, (bid >> 7) * 128);
  } else {
    int sid = bid - 768;
    int i0 = (sid & 15) * 32, j0 = (sid >> 4) * 32;
    float (*sA)[68] = (float(*)[68])(&As[0][0][0]);   // 8.7 KB, fits in As
    float (*sB)[68] = (float(*)[68])(&Bs[0][0][0]);
    int tx = t & 15, ty = t >> 4;
    float acc00 = 0.f, acc01 = 0.f, acc10 = 0.f, acc11 = 0.f;
    for (int k0 = 0; k0 < DIMX; k0 += 64) {
#pragma unroll
      for (int c = t; c < 512; c += 256) {
        int r = c >> 4, cc = (c & 15) * 4;
        *(float4*)&sA[r][cc] = *(const float4*)&normed[(size_t)(i0 + r)*DIMX + k0 + cc];
        *(float4*)&sB[r][cc] = *(const float4*)&normed[(size_t)(j0 + r)*DIMX + k0 + cc];
      }
      __syncthreads();
#pragma unroll 16
      for (int kk = 0; kk < 64; ++kk) {
        float a0 = sA[ty*2][kk],   a1 = sA[ty*2+1][kk];
        float b0 = sB[tx*2][kk],   b1 = sB[tx*2+1][kk];
        acc00 += a0*b0; acc01 += a0*b1; acc10 += a1*b0; acc11 += a1*b1;
      }
      __syncthreads();
    }
    sims[(size_t)(i0+ty*2  )*BATCH + j0+tx*2  ] = acc00;
    sims[(size_t)(i0+ty*2  )*BATCH + j0+tx*2+1] = acc01;
    sims[(size_t)(i0+ty*2+1)*BATCH + j0+tx*2  ] = acc10;
    sims[(size_t)(i0+ty*2+1)*BATCH + j0+tx*2+1] = acc11;
  }
}

// ---------------- K3: top-17 via rank selection (exact lax.top_k order) ------------------------
__global__ __launch_bounds__(256, 8) void topk_rank(const float* __restrict__ sims,
                                                    int* __restrict__ knn) {
  int i = blockIdx.x, t = threadIdx.x;
  __shared__ float row[BATCH];
  row[t]       = sims[(size_t)i*BATCH + t];
  row[t + 256] = sims[(size_t)i*BATCH + t + 256];
  __syncthreads();
  float v1 = row[t], v2 = row[t + 256];
  int i1 = t, i2 = t + 256;
  int r1 = 0, r2 = 0;
  const float4* r4 = (const float4*)row;
#pragma unroll 8
  for (int c = 0; c < BATCH/4; ++c) {
    float4 q = r4[c];            // LDS broadcast (same addr all lanes)
    int base = c * 4;
    r1 += (q.x > v1 || (q.x == v1 && base+0 < i1));
    r1 += (q.y > v1 || (q.y == v1 && base+1 < i1));
    r1 += (q.z > v1 || (q.z == v1 && base+2 < i1));
    r1 += (q.w > v1 || (q.w == v1 && base+3 < i1));
    r2 += (q.x > v2 || (q.x == v2 && base+0 < i2));
    r2 += (q.y > v2 || (q.y == v2 && base+1 < i2));
    r2 += (q.z > v2 || (q.z == v2 && base+2 < i2));
    r2 += (q.w > v2 || (q.w == v2 && base+3 < i2));
  }
  if (r1 < KNN) knn[i*32 + r1] = i1;
  if (r2 < KNN) knn[i*32 + r2] = i2;
}

// ---------------- K4: attention, 2 features per phase-pair (champion structure) ---------------
#define NF_BLK 8
__global__ __launch_bounds__(256, 8) void attn_kernel(
    const ushort_t* __restrict__ qkv, const int* __restrict__ knn,
    ushort_t* __restrict__ attn_out) {
  int b = blockIdx.x, g = blockIdx.y, t = threadIdx.x;
  int n0 = g * NF_BLK;
  __shared__ float sc_s[2][KNN][HEADS];
  __shared__ int idxp[KNN];            // precomputed qkv row offset: idx*NFEAT*QKV_W
  if (t < KNN) idxp[t] = knn[b*32 + t] * (NFEAT*QKV_W);
  __syncthreads();

  for (int np = 0; np < NF_BLK; np += 2) {
    int n = n0 + np;
    // ---- phase A: scores for features n, n+1 (272 jobs over 256 lanes) ----
    for (int job = t; job < 2*KNN*HEADS; job += 256) {
      int f = (job >= KNN*HEADS) ? 1 : 0;
      int r = job - f*KNN*HEADS;
      int j = r >> 3, h = r & 7;
      const uint4* qp = (const uint4*)&qkv[(size_t)(b*NFEAT + n + f)*QKV_W + h*DHEAD];
      const uint4* kp = (const uint4*)&qkv[(size_t)(idxp[j] + (n + f)*QKV_W + 256 + h*DHEAD)];
      float s0 = 0.f, s1 = 0.f;
#pragma unroll
      for (int i = 0; i < 4; ++i) {
        uint4 qv = qp[i], kv = kp[i];
        s0 = dot2bf(kv.x, qv.x, s0); s1 = dot2bf(kv.y, qv.y, s1);
        s0 = dot2bf(kv.z, qv.z, s0); s1 = dot2bf(kv.w, qv.w, s1);
      }
      sc_s[f][j][h] = (s0 + s1) * SCALE_L2;
    }
    __syncthreads();
    // ---- phase B: register softmax (exp2, in-place) + PV direct from global ----
    {
      int f = t >> 7, p = t & 127, h = p >> 4;
      float sv[KNN];
#pragma unroll
      for (int j = 0; j < KNN; ++j) sv[j] = sc_s[f][j][h];
      float m = sv[0];
#pragma unroll
      for (int j = 1; j < KNN; ++j) m = fmaxf(m, sv[j]);
      float sum = 0.f;
#pragma unroll
      for (int j = 0; j < KNN; ++j) { sv[j] = EXP2(sv[j] - m); sum += sv[j]; }
      float inv = 1.0f / sum;
      int voff = (n + f)*QKV_W + 512 + p*2;
      float alo = 0.f, ahi = 0.f;
#pragma unroll
      for (int j = 0; j < KNN; ++j) {
        uint wv = *(const uint*)&qkv[(size_t)(idxp[j] + voff)];
        alo += sv[j] * bf_lo(wv);
        ahi += sv[j] * bf_hi(wv);
      }
      *(uint*)&attn_out[(size_t)(b*NFEAT + n + f)*DIMX + p*2] =
          (uint)f2bf(alo * inv) | ((uint)f2bf(ahi * inv) << 16);
    }
    __syncthreads();
  }
}

extern "C" void kernel_launch(void* const* d_in, const int* in_sizes, int n_in,
                              void* d_out, int out_size, void* d_ws, size_t ws_size,
                              hipStream_t stream) {
  const float* x      = (const float*)d_in[0];
  const float* W_qkv  = (const float*)d_in[1];
  const float* W_out  = (const float*)d_in[2];
  const float* b_out  = (const float*)d_in[3];
  const float* W_repr = (const float*)d_in[4];
  const float* b_repr = (const float*)d_in[5];
  float* out = (float*)d_out;

  ushort_t* qkv      = (ushort_t*)d_ws;                        // 16384*768 bf16
  ushort_t* xbf      = qkv + (size_t)16384*QKV_W;              // 16384*256
  ushort_t* wqT      = xbf + (size_t)16384*DIMX;               // 768*256
  ushort_t* woT      = wqT + (size_t)QKV_W*DIMX;               // 256*256
  ushort_t* attn_out = woT + (size_t)DIMX*DIMX;                // 16384*256
  float*    normed   = (float*)(attn_out + (size_t)16384*DIMX);
  float*    sims     = normed + (size_t)BATCH*DIMX;            // 512*512 f32
  int*      knn      = (int*)(sims + (size_t)BATCH*BATCH);

  repr_prep_kernel<<<BATCH + 64, 256, 0, stream>>>(
      x, W_repr, b_repr, W_qkv, W_out, normed, xbf, wqT, woT);
  simqkv_kernel<<<768 + 256, 256, 0, stream>>>(xbf, wqT, qkv, normed, sims);
  topk_rank<<<BATCH, 256, 0, stream>>>(sims, knn);
  attn_kernel<<<dim3(BATCH, NFEAT/NF_BLK), 256, 0, stream>>>(qkv, knn, attn_out);
  mfma_gemm<true><<<dim3(128, 2), 256, 0, stream>>>(
      attn_out, woT, out, b_out, 16384, DIMX, DIMX);
}